// Round 6
// baseline (412.764 us; speedup 1.0000x reference)
//
#include <hip/hip_runtime.h>

typedef unsigned short u16;
typedef unsigned int u32;
typedef float f32x4 __attribute__((ext_vector_type(4)));
typedef short i16x8 __attribute__((ext_vector_type(8)));
typedef __bf16 bf16x8_t __attribute__((ext_vector_type(8)));

#define LQ 43054

__device__ __forceinline__ float bf2f(u16 u) {
  union { u32 i; float f; } v; v.i = ((u32)u) << 16; return v.f;
}
__device__ __forceinline__ u16 f2bf(float f) {
  u32 i = __float_as_uint(f);
  return (u16)((i + 0x7FFFu + ((i >> 16) & 1u)) >> 16);
}

// D = S0.lo*S1.lo + S0.hi*S1.hi + S2  (bf16 pairs, f32 accumulate)
__device__ __forceinline__ float dot2bf(u32 v, u32 w, float c) {
  float d;
  asm("v_dot2_f32_bf16 %0, %1, %2, %3" : "=v"(d) : "v"(v), "v"(w), "v"(c));
  return d;
}

// ---- MFMA wrapper robust to builtin operand type (V8 short vs V8 __bf16) ----
template <typename T>
__device__ __forceinline__ auto mfma_try(T a, T b, f32x4 c, int)
    -> decltype(__builtin_amdgcn_mfma_f32_16x16x32_bf16(a, b, c, 0, 0, 0)) {
  return __builtin_amdgcn_mfma_f32_16x16x32_bf16(a, b, c, 0, 0, 0);
}
template <typename T>
__device__ __forceinline__ f32x4 mfma_try(T a, T b, f32x4 c, long) {
  return __builtin_amdgcn_mfma_f32_16x16x32_bf16(
      __builtin_bit_cast(bf16x8_t, a), __builtin_bit_cast(bf16x8_t, b), c, 0, 0, 0);
}
__device__ __forceinline__ f32x4 mfma_bf16(i16x8 a, i16x8 b, f32x4 c) {
  return mfma_try(a, b, c, 0);
}

// ---- all 6 weight transposes in one kernel: f32 (256 x N) -> bf16 (N x 256) ----
__global__ void transpose_all_kernel(
    const float* __restrict__ w_off, const float* __restrict__ w_attn,
    const float* __restrict__ w_val, const float* __restrict__ w_out,
    const float* __restrict__ w1, const float* __restrict__ w2,
    u16* __restrict__ wT) {
  int b = blockIdx.x;
  const float* src; u16* dst; int N; int col;
  if (b < 256)       { src = w_off;  dst = wT;          N = 256; col = b; }
  else if (b < 384)  { src = w_attn; dst = wT + 65536;  N = 128; col = b - 256; }
  else if (b < 640)  { src = w_val;  dst = wT + 98304;  N = 256; col = b - 384; }
  else if (b < 896)  { src = w_out;  dst = wT + 163840; N = 256; col = b - 640; }
  else if (b < 1152) { src = w1;     dst = wT + 229376; N = 256; col = b - 896; }
  else               { src = w2;     dst = wT + 294912; N = 256; col = b - 1152; }
  dst[col * 256 + threadIdx.x] = f2bf(src[threadIdx.x * N + col]);
}

// ================= shared helpers ==========================================
// load one 16-col B tile's 8 K-fragments into registers
__device__ __forceinline__ void load_b(i16x8* f, const u16* Bt, int t, int l16, int quad) {
  const uint4* bp = (const uint4*)Bt + (t * 16 + l16) * 32 + quad;
#pragma unroll
  for (int kk = 0; kk < 8; ++kk) f[kk] = __builtin_bit_cast(i16x8, bp[kk << 2]);
}
// 16 MFMAs of one tile over 2 row-groups (32-row blocks)
__device__ __forceinline__ void tile_mfma2(f32x4* acc, const uint4* As,
                                           const i16x8* bfr, int l16, int quad) {
#pragma unroll
  for (int rg = 0; rg < 2; ++rg) {
    int arow = rg * 16 + l16;
    f32x4 a = {0.f, 0.f, 0.f, 0.f};
#pragma unroll
    for (int kk = 0; kk < 8; ++kk) {
      i16x8 afr = __builtin_bit_cast(i16x8, As[arow * 32 + (((kk << 2) + quad) ^ (arow & 7))]);
      a = mfma_bf16(afr, bfr[kk], a);
    }
    acc[rg] = a;
  }
}

// u16 index into a GEMM-A swizzled LDS tile for element (row, col)
__device__ __forceinline__ int swz_u16(int row, int col) {
  return row * 256 + ((((col >> 3) ^ (row & 7)) << 3) | (col & 7));
}

// LDS output staging: u16 rows with stride 264 (528 B: 16B-aligned, bank-skewed).
#define LS_STRIDE 264

// per-head softmax over 16 cols (l16 lanes) -> aw
__device__ __forceinline__ void attn_softmax_store(
    const f32x4* acc, int t, const float* __restrict__ b_attn,
    float* __restrict__ aw, int r0, int M, int quad, int l16) {
  const int colc = t * 16 + l16;
  const float bv = b_attn[colc];
#pragma unroll
  for (int rg = 0; rg < 2; ++rg)
#pragma unroll
    for (int r = 0; r < 4; ++r) {
      float v = acc[rg][r] + bv;
      float m = v;
#pragma unroll
      for (int o = 1; o < 16; o <<= 1) m = fmaxf(m, __shfl_xor(m, o));
      float e = __expf(v - m);
      float s = e;
#pragma unroll
      for (int o = 1; o < 16; o <<= 1) s += __shfl_xor(s, o);
      int row = r0 + rg * 16 + (quad << 2) + r;
      if (row < M) aw[row * 128 + colc] = e / s;
    }
}

// ---- fused head: value GEMM + offsets GEMM + attn softmax, one query read ----
// 32 rows/block, 4 blocks/CU. Rolling B double-buffer: load of tile t+1 issued
// before the MFMAs of tile t (incl. across phases; drained at barriers after
// overlapping epilogue VALU). Arithmetic identical to round 5.
__global__ __launch_bounds__(256, 4) void valoff_kernel(
    const float* __restrict__ query, const float* __restrict__ pos,
    const u16* __restrict__ wvalT, const float* __restrict__ b_val,
    const u16* __restrict__ woffT, const float* __restrict__ b_off,
    const float* __restrict__ b_attn,
    u16* __restrict__ value, u16* __restrict__ offb, float* __restrict__ aw,
    int M) {
  __shared__ uint4 smem[2112];   // 33,792 B
  uint4* Aq  = smem;             // 17,408 B region: bf16(query); reused as LS
  uint4* Aqp = smem + 1088;      // 16 KB: bf16(query+pos)
  const int tid = threadIdx.x;
  const int w = tid >> 6, lane = tid & 63, quad = lane >> 4, l16 = lane & 15;
  const int r0 = blockIdx.x * 32;
  // ---- stage: single query+pos read -> both A tiles ----
#pragma unroll
  for (int h = 0; h < 2; ++h) {
    float4 vq[4], vp[4];
#pragma unroll
    for (int it = 0; it < 4; ++it) {
      int e = tid + (h * 4 + it) * 256;
      int gr = min(r0 + (e >> 6), M - 1);
      int idx = gr * 64 + (e & 63);
      vq[it] = ((const float4*)query)[idx];
      vp[it] = ((const float4*)pos)[idx];
    }
#pragma unroll
    for (int it = 0; it < 4; ++it) {
      int e = tid + (h * 4 + it) * 256;
      int row = e >> 6, c4 = e & 63;
      int c = c4 >> 1, hf = c4 & 1;
      int sidx = ((row * 32 + (c ^ (row & 7))) << 1) | hf;
      uint2 pkq, pks;
      pkq.x = (u32)f2bf(vq[it].x) | ((u32)f2bf(vq[it].y) << 16);
      pkq.y = (u32)f2bf(vq[it].z) | ((u32)f2bf(vq[it].w) << 16);
      float sx = vq[it].x + vp[it].x, sy = vq[it].y + vp[it].y;
      float sz = vq[it].z + vp[it].z, sw = vq[it].w + vp[it].w;
      pks.x = (u32)f2bf(sx) | ((u32)f2bf(sy) << 16);
      pks.y = (u32)f2bf(sz) | ((u32)f2bf(sw) << 16);
      ((uint2*)Aq)[sidx] = pkq;
      ((uint2*)Aqp)[sidx] = pks;
    }
  }
  i16x8 bfrA[8], bfrB[8];
  load_b(bfrA, wvalT, w * 4 + 0, l16, quad);   // prefetch value t0
  __syncthreads();  // S1
  f32x4 vals[4][2];
  // ---- value phase (Aq @ wvalT), rolling prefetch ----
  load_b(bfrB, wvalT, w * 4 + 1, l16, quad);
  tile_mfma2(vals[0], Aq, bfrA, l16, quad);
  load_b(bfrA, wvalT, w * 4 + 2, l16, quad);
  tile_mfma2(vals[1], Aq, bfrB, l16, quad);
  load_b(bfrB, wvalT, w * 4 + 3, l16, quad);
  tile_mfma2(vals[2], Aq, bfrA, l16, quad);
  load_b(bfrA, woffT, 16 + w, l16, quad);      // prefetch attn t0
  tile_mfma2(vals[3], Aq, bfrB, l16, quad);
  // ---- attn phase (Aqp @ wattnT) + per-head softmax ----
  {
    f32x4 acc[2];
    load_b(bfrB, woffT, 16 + w + 4, l16, quad);  // prefetch attn t1
    tile_mfma2(acc, Aqp, bfrA, l16, quad);
    attn_softmax_store(acc, w, b_attn, aw, r0, M, quad, l16);
    load_b(bfrA, woffT, w * 4 + 0, l16, quad);   // prefetch off t0 (drains @ S2)
    tile_mfma2(acc, Aqp, bfrB, l16, quad);
    attn_softmax_store(acc, w + 4, b_attn, aw, r0, M, quad, l16);
  }
  __syncthreads();  // S2: all Aq reads done
  // ---- value epilogue via LS (over dead Aq region), vectorized stores ----
  u16* Ls = (u16*)smem;
#pragma unroll
  for (int i = 0; i < 4; ++i) {
    const int col = (w * 4 + i) * 16 + l16;
    const float bv = b_val[col];
#pragma unroll
    for (int rg = 0; rg < 2; ++rg)
#pragma unroll
      for (int r = 0; r < 4; ++r)
        Ls[(rg * 16 + (quad << 2) + r) * LS_STRIDE + col] = f2bf(vals[i][rg][r] + bv);
  }
  __syncthreads();  // S3
#pragma unroll
  for (int it = 0; it < 4; ++it) {
    int lrow = w * 8 + it * 2 + (lane >> 5);
    int grow = r0 + lrow;
    if (grow < M)
      *(uint4*)(value + (size_t)grow * 256 + (lane & 31) * 8) =
          *(const uint4*)(Ls + lrow * LS_STRIDE + (lane & 31) * 8);
  }
  // ---- off phase (Aqp @ woffT); value stores drain at S4, overlapped ----
  load_b(bfrB, woffT, w * 4 + 1, l16, quad);
  tile_mfma2(vals[0], Aqp, bfrA, l16, quad);
  load_b(bfrA, woffT, w * 4 + 2, l16, quad);
  tile_mfma2(vals[1], Aqp, bfrB, l16, quad);
  load_b(bfrB, woffT, w * 4 + 3, l16, quad);
  tile_mfma2(vals[2], Aqp, bfrA, l16, quad);
  tile_mfma2(vals[3], Aqp, bfrB, l16, quad);
  __syncthreads();  // S4: value-store LS reads done
#pragma unroll
  for (int i = 0; i < 4; ++i) {
    const int col = (w * 4 + i) * 16 + l16;
    const float bv = b_off[col];
#pragma unroll
    for (int rg = 0; rg < 2; ++rg)
#pragma unroll
      for (int r = 0; r < 4; ++r)
        Ls[(rg * 16 + (quad << 2) + r) * LS_STRIDE + col] = f2bf(vals[i][rg][r] + bv);
  }
  __syncthreads();  // S5
#pragma unroll
  for (int it = 0; it < 4; ++it) {
    int lrow = w * 8 + it * 2 + (lane >> 5);
    int grow = r0 + lrow;
    if (grow < M)
      *(uint4*)(offb + (size_t)grow * 256 + (lane & 31) * 8) =
          *(const uint4*)(Ls + lrow * LS_STRIDE + (lane & 31) * 8);
  }
}

// ---- fused tail: out-proj -> +query -> LN1 -> FFN1(relu) -> FFN2 -> +x -> LN2 ----
// 32 rows/block (4 blocks/CU), rolling B double-buffer across all 12 tiles.
__global__ __launch_bounds__(256, 4) void tail_fused_kernel(
    const u16* __restrict__ accb, const u16* __restrict__ woutT,
    const float* __restrict__ b_out, const float* __restrict__ query,
    const float* __restrict__ g1, const float* __restrict__ beta1,
    const u16* __restrict__ w1T, const float* __restrict__ b1,
    const u16* __restrict__ w2T, const float* __restrict__ b2,
    const float* __restrict__ g2, const float* __restrict__ beta2,
    float* __restrict__ out, int M) {
  __shared__ uint4 smem[2112];             // 33,792 B total
  uint4* As = smem;                        // 16 KB: accb stage, then h
  uint4* Xs = smem + 1024;                 // 16 KB: x (LN1 out)
  float2* pnorm = (float2*)(smem + 2048);  // 1 KB
  const int tid = threadIdx.x;
  const int w = tid >> 6, lane = tid & 63, quad = lane >> 4, l16 = lane & 15;
  const int r0 = blockIdx.x * 32;
#pragma unroll
  for (int jj = 0; jj < 4; ++jj) {
    int row = w * 8 + jj * 2 + (lane >> 5);
    int gr = min(r0 + row, M - 1);
    int c = lane & 31;
    const uint4* gp = (const uint4*)accb + (size_t)gr * 32 + (c ^ (row & 7));
    __builtin_amdgcn_global_load_lds(
        (const __attribute__((address_space(1))) void*)gp,
        (__attribute__((address_space(3))) void*)(As + (w * 8 + jj * 2) * 32),
        16, 0, 0);
  }
  i16x8 bfrA[8], bfrB[8];
  load_b(bfrA, woutT, w * 4 + 0, l16, quad);  // prefetch out-proj t0
  __syncthreads();
  f32x4 vals[4][2];
  float s[8], s2[8];

  // ---------- stage 1: out-proj GEMM (rolling prefetch) ----------
  load_b(bfrB, woutT, w * 4 + 1, l16, quad);
  tile_mfma2(vals[0], As, bfrA, l16, quad);
  load_b(bfrA, woutT, w * 4 + 2, l16, quad);
  tile_mfma2(vals[1], As, bfrB, l16, quad);
  load_b(bfrB, woutT, w * 4 + 3, l16, quad);
  tile_mfma2(vals[2], As, bfrA, l16, quad);
  load_b(bfrA, w1T, w * 4 + 0, l16, quad);    // prefetch FFN1 t0 (overlaps epilogue)
  tile_mfma2(vals[3], As, bfrB, l16, quad);
  // bias + query resid + LN1 stats
#pragma unroll
  for (int k = 0; k < 8; ++k) { s[k] = 0.f; s2[k] = 0.f; }
#pragma unroll
  for (int i = 0; i < 4; ++i) {
    const int col = (w * 4 + i) * 16 + l16;
    const float bv = b_out[col];
#pragma unroll
    for (int rg = 0; rg < 2; ++rg)
#pragma unroll
      for (int r = 0; r < 4; ++r) {
        int row = r0 + rg * 16 + (quad << 2) + r;
        float rv = (row < M) ? query[row * 256 + col] : 0.f;
        float v = vals[i][rg][r] + bv + rv;
        vals[i][rg][r] = v;
        s[rg * 4 + r] += v; s2[rg * 4 + r] += v * v;
      }
  }
#pragma unroll
  for (int k = 0; k < 8; ++k)
#pragma unroll
    for (int o = 1; o < 16; o <<= 1) {
      s[k] += __shfl_xor(s[k], o);
      s2[k] += __shfl_xor(s2[k], o);
    }
  if (l16 == 0) {
#pragma unroll
    for (int rg = 0; rg < 2; ++rg)
#pragma unroll
      for (int r = 0; r < 4; ++r)
        pnorm[(rg * 16 + (quad << 2) + r) * 4 + w] = make_float2(s[rg * 4 + r], s2[rg * 4 + r]);
  }
  __syncthreads();
  u16* Xu = (u16*)Xs;
#pragma unroll
  for (int rg = 0; rg < 2; ++rg)
#pragma unroll
    for (int r = 0; r < 4; ++r) {
      int lrow = rg * 16 + (quad << 2) + r;
      float4 p01 = ((const float4*)pnorm)[lrow * 2];
      float4 p23 = ((const float4*)pnorm)[lrow * 2 + 1];
      float ss = p01.x + p01.z + p23.x + p23.z;
      float qq = p01.y + p01.w + p23.y + p23.w;
      float mean = ss * (1.f / 256.f);
      float var = qq * (1.f / 256.f) - mean * mean;
      float inv = rsqrtf(var + 1e-5f);
#pragma unroll
      for (int i = 0; i < 4; ++i) {
        const int col = (w * 4 + i) * 16 + l16;
        float o = (vals[i][rg][r] - mean) * inv * g1[col] + beta1[col];
        Xu[swz_u16(lrow, col)] = f2bf(o);
      }
    }
  __syncthreads();

  // ---------- stage 2: FFN1 = relu(x @ w1 + b1) -> h into As ----------
  load_b(bfrB, w1T, w * 4 + 1, l16, quad);
  tile_mfma2(vals[0], Xs, bfrA, l16, quad);
  load_b(bfrA, w1T, w * 4 + 2, l16, quad);
  tile_mfma2(vals[1], Xs, bfrB, l16, quad);
  load_b(bfrB, w1T, w * 4 + 3, l16, quad);
  tile_mfma2(vals[2], Xs, bfrA, l16, quad);
  load_b(bfrA, w2T, w * 4 + 0, l16, quad);    // prefetch FFN2 t0 (overlaps epilogue)
  tile_mfma2(vals[3], Xs, bfrB, l16, quad);
  u16* Hu = (u16*)As;
#pragma unroll
  for (int i = 0; i < 4; ++i) {
    const int col = (w * 4 + i) * 16 + l16;
    const float bv = b1[col];
#pragma unroll
    for (int rg = 0; rg < 2; ++rg)
#pragma unroll
      for (int r = 0; r < 4; ++r) {
        int lrow = rg * 16 + (quad << 2) + r;
        Hu[swz_u16(lrow, col)] = f2bf(fmaxf(vals[i][rg][r] + bv, 0.f));
      }
  }
  __syncthreads();

  // ---------- stage 3: FFN2 = h @ w2 + b2 + x, LN2 stats ----------
  load_b(bfrB, w2T, w * 4 + 1, l16, quad);
  tile_mfma2(vals[0], As, bfrA, l16, quad);
  load_b(bfrA, w2T, w * 4 + 2, l16, quad);
  tile_mfma2(vals[1], As, bfrB, l16, quad);
  load_b(bfrB, w2T, w * 4 + 3, l16, quad);
  tile_mfma2(vals[2], As, bfrA, l16, quad);
  tile_mfma2(vals[3], As, bfrB, l16, quad);
#pragma unroll
  for (int k = 0; k < 8; ++k) { s[k] = 0.f; s2[k] = 0.f; }
#pragma unroll
  for (int i = 0; i < 4; ++i) {
    const int col = (w * 4 + i) * 16 + l16;
    const float bv = b2[col];
#pragma unroll
    for (int rg = 0; rg < 2; ++rg)
#pragma unroll
      for (int r = 0; r < 4; ++r) {
        int lrow = rg * 16 + (quad << 2) + r;
        float xv = bf2f(Xu[swz_u16(lrow, col)]);
        float v = vals[i][rg][r] + bv + xv;
        vals[i][rg][r] = v;
        s[rg * 4 + r] += v; s2[rg * 4 + r] += v * v;
      }
  }
#pragma unroll
  for (int k = 0; k < 8; ++k)
#pragma unroll
    for (int o = 1; o < 16; o <<= 1) {
      s[k] += __shfl_xor(s[k], o);
      s2[k] += __shfl_xor(s2[k], o);
    }
  if (l16 == 0) {
#pragma unroll
    for (int rg = 0; rg < 2; ++rg)
#pragma unroll
      for (int r = 0; r < 4; ++r)
        pnorm[(rg * 16 + (quad << 2) + r) * 4 + w] = make_float2(s[rg * 4 + r], s2[rg * 4 + r]);
  }
  __syncthreads();
  float* stg = (float*)smem;
#pragma unroll
  for (int rg = 0; rg < 2; ++rg) {
#pragma unroll
    for (int r = 0; r < 4; ++r) {
      int lrow = rg * 16 + (quad << 2) + r;
      float4 p01 = ((const float4*)pnorm)[lrow * 2];
      float4 p23 = ((const float4*)pnorm)[lrow * 2 + 1];
      float ss = p01.x + p01.z + p23.x + p23.z;
      float qq = p01.y + p01.w + p23.y + p23.w;
      float mean = ss * (1.f / 256.f);
      float var = qq * (1.f / 256.f) - mean * mean;
      float inv = rsqrtf(var + 1e-5f);
#pragma unroll
      for (int i = 0; i < 4; ++i) {
        const int col = (w * 4 + i) * 16 + l16;
        stg[((quad << 2) + r) * 268 + col] = (vals[i][rg][r] - mean) * inv * g2[col] + beta2[col];
      }
    }
    __syncthreads();
#pragma unroll
    for (int rr = 0; rr < 4; ++rr) {
      int lr = w * 4 + rr;
      int grow = r0 + rg * 16 + lr;
      if (grow < M)
        *(float4*)(out + (size_t)grow * 256 + lane * 4) =
            *(const float4*)(stg + lr * 268 + lane * 4);
    }
    if (rg == 0) __syncthreads();
  }
}

// ---- fused prep + deformable sampling: one block = 2 queries (round-2 config,
// measured 75.4 us: 2*LQ waves of TLP, u32 taps, dot2 accumulate) ----
__global__ __launch_bounds__(256) void sampler_kernel(
    const float* __restrict__ refp, const u16* __restrict__ offb,
    const float* __restrict__ aw, const u16* __restrict__ value,
    u32* __restrict__ accv) {
  __shared__ uint4 rec[272];
  const int t = threadIdx.x;
  const int b = blockIdx.x;
  {
    const int qs = t >> 7, j = t & 127;
    const int i = b * 2 + qs;
    const int h = j >> 4, lp = j & 15, l = lp >> 2;
    const int Wl = (l == 0) ? 180 : (l == 1) ? 90 : (l == 2) ? 45 : 23;
    const int st = (l == 0) ? 0 : (l == 1) ? 32400 : (l == 2) ? 40500 : 42525;
    const float wj = aw[i * 128 + j];
    const u32 o2 = *(const u32*)(offb + i * 256 + h * 32 + lp * 2);
    const float ox = bf2f((u16)(o2 & 0xffffu)), oy = bf2f((u16)(o2 >> 16));
    const float rx = refp[i * 8 + l * 2], ry = refp[i * 8 + l * 2 + 1];
    float x = rx * (float)Wl + ox - 0.5f;
    float y = ry * (float)Wl + oy - 0.5f;
    float x0f = floorf(x), y0f = floorf(y);
    float fx = x - x0f, fy = y - y0f;
    int x0 = (int)x0f, y0 = (int)y0f;
    bool vx0 = (x0 >= 0) & (x0 < Wl), vx1 = (x0 + 1 >= 0) & (x0 + 1 < Wl);
    bool vy0 = (y0 >= 0) & (y0 < Wl), vy1 = (y0 + 1 >= 0) & (y0 + 1 < Wl);
    int x0c = min(max(x0, 0), Wl - 1), x1c = min(max(x0 + 1, 0), Wl - 1);
    int y0c = min(max(y0, 0), Wl - 1), y1c = min(max(y0 + 1, 0), Wl - 1);
    float w00 = (vx0 & vy0) ? wj * (1.f - fx) * (1.f - fy) : 0.f;
    float w01 = (vx1 & vy0) ? wj * fx * (1.f - fy) : 0.f;
    float w10 = (vx0 & vy1) ? wj * (1.f - fx) * fy : 0.f;
    float w11 = (vx1 & vy1) ? wj * fx * fy : 0.f;
    uint4 r;
    r.x = (u32)((st + y0c * Wl + x0c) * 512 + h * 64) | (u32)(x1c - x0c);
    r.y = (u32)(y1c - y0c) * (u32)(Wl * 512);
    r.z = (u32)f2bf(w00) | ((u32)f2bf(w01) << 16);
    r.w = (u32)f2bf(w10) | ((u32)f2bf(w11) << 16);
    rec[qs * 136 + h * 17 + lp] = r;
  }
  __syncthreads();
  const int qs = t >> 7, j = t & 127;
  const int h = j >> 4, dp = j & 15;
  const char* vb = (const char*)value;
  float a0 = 0.f, a1 = 0.f;
  const int rbase = qs * 136 + h * 17;
  const u32 dp4 = (u32)(dp * 4);
#pragma unroll
  for (int p = 0; p < 16; ++p) {
    uint4 r = rec[rbase + p];
    u32 base = (r.x & 0xFFFFFFFEu) + dp4;
    u32 dxo = (r.x & 1u) << 9;
    u32 dyo = r.y;
    u32 p00 = *(const u32*)(vb + base);
    u32 p01 = *(const u32*)(vb + base + dxo);
    u32 p10 = *(const u32*)(vb + base + dyo);
    u32 p11 = *(const u32*)(vb + base + dyo + dxo);
    a0 = dot2bf(__builtin_amdgcn_perm(p01, p00, 0x05040100u), r.z, a0);
    a1 = dot2bf(__builtin_amdgcn_perm(p01, p00, 0x07060302u), r.z, a1);
    a0 = dot2bf(__builtin_amdgcn_perm(p11, p10, 0x05040100u), r.w, a0);
    a1 = dot2bf(__builtin_amdgcn_perm(p11, p10, 0x07060302u), r.w, a1);
  }
  u32 pk = (u32)f2bf(a0) | ((u32)f2bf(a1) << 16);
  accv[(b * 2 + qs) * 128 + j] = pk;
}

extern "C" void kernel_launch(void* const* d_in, const int* in_sizes, int n_in,
                              void* d_out, int out_size, void* d_ws, size_t ws_size,
                              hipStream_t stream) {
  const float* query  = (const float*)d_in[0];
  const float* refp   = (const float*)d_in[1];
  const float* pos    = (const float*)d_in[2];
  const float* w_off  = (const float*)d_in[5];
  const float* b_off  = (const float*)d_in[6];
  const float* w_attn = (const float*)d_in[7];
  const float* b_attn = (const float*)d_in[8];
  const float* w_val  = (const float*)d_in[9];
  const float* b_val  = (const float*)d_in[10];
  const float* w_out  = (const float*)d_in[11];
  const float* b_out  = (const float*)d_in[12];
  const float* g1     = (const float*)d_in[13];
  const float* beta1  = (const float*)d_in[14];
  const float* w1     = (const float*)d_in[15];
  const float* b1     = (const float*)d_in[16];
  const float* w2     = (const float*)d_in[17];
  const float* b2     = (const float*)d_in[18];
  const float* g2     = (const float*)d_in[19];
  const float* beta2  = (const float*)d_in[20];

  char* ws = (char*)d_ws;
  u16*   wT    = (u16*)(ws + 0);            //   720,896, live whole launch
  u16*   value = (u16*)(ws + 720896);       // dead after sampler
  u16*   offb  = (u16*)(ws + 22764544);     // dead after sampler
  float* aw    = (float*)(ws + 44808192);   // dead after sampler
  u16*   accb  = (u16*)(ws + 66851840);     // dead after tail

  u16* woffT  = wT;                // 256 rows; wattnT contiguous after (384-row B)
  u16* wvalT  = wT + 98304;
  u16* woutT  = wT + 163840;
  u16* w1T    = wT + 229376;
  u16* w2T    = wT + 294912;

  transpose_all_kernel<<<1408, 256, 0, stream>>>(w_off, w_attn, w_val, w_out, w1, w2, wT);

  const int gh = (LQ + 31) / 32;  // 1346
  valoff_kernel<<<gh, 256, 0, stream>>>(query, pos, wvalT, b_val, woffT, b_off, b_attn,
                                        value, offb, aw, LQ);
  sampler_kernel<<<LQ / 2, 256, 0, stream>>>(refp, offb, aw, value, (u32*)accb);
  tail_fused_kernel<<<gh, 256, 0, stream>>>(accb, woutT, b_out, query, g1, beta1,
                                            w1T, b1, w2T, b2, g2, beta2,
                                            (float*)d_out, LQ);
}